// Round 1
// baseline (1140.497 us; speedup 1.0000x reference)
//
#include <hip/hip_runtime.h>
#include <cstddef>

#define T_LEN 1000
#define B_SZ 64
#define C_IN_ 12
#define D_MODEL_ 128
#define D_INNER_ 256
#define D_STATE_ 16
#define DT_RANK_ 8
#define N_CLS 5

__device__ __forceinline__ float sigmoid_f(float x) {
  if (x >= 0.f) return 1.f / (1.f + expf(-x));
  float e = expf(x);
  return e / (1.f + e);
}
__device__ __forceinline__ float softplus_f(float x) {
  return (x > 0.f) ? (x + log1pf(expf(-x))) : log1pf(expf(x));
}

// K1: fused  h = x@ip_w.T + ip_b  ->  xm = h@W1.T  -> causal depthwise conv -> silu -> u
// Tile: 64 output t-rows per block, 3-row halo recomputed (xm rows t0-3..t0+63).
__global__ __launch_bounds__(256) void k1_u(
    const float* __restrict__ x, const float* __restrict__ ip_w,
    const float* __restrict__ ip_b, const float* __restrict__ in_proj_w,
    const float* __restrict__ conv_w, const float* __restrict__ conv_b,
    float* __restrict__ u_out)
{
  __shared__ float h_s[67][129];    // pad 129: 8-row stride -> 2-way bank alias (free)
  __shared__ float xm_s[67][257];
  __shared__ float w_s[256][33];    // W1 chunk, n-major, pad 33 (coprime with 32)
  __shared__ float xa[67][C_IN_];
  __shared__ float ipw_s[D_MODEL_][C_IN_];
  __shared__ float cw_s[D_INNER_][4];
  __shared__ float cb_s[D_INNER_];

  const int tile = blockIdx.x;   // 0..15
  const int b    = blockIdx.y;   // 0..63
  const int t0   = tile * 64;
  const int tid  = threadIdx.x;

  // stage x rows (with halo, zero-padded), ip_w, conv params
  for (int f = tid; f < 67 * C_IN_; f += 256) {
    int r = f / C_IN_, c = f - r * C_IN_;
    int t = t0 - 3 + r;
    xa[r][c] = (t >= 0 && t < T_LEN) ? x[((size_t)b * T_LEN + t) * C_IN_ + c] : 0.f;
  }
  for (int f = tid; f < D_MODEL_ * C_IN_; f += 256) ipw_s[f / C_IN_][f % C_IN_] = ip_w[f];
  for (int f = tid; f < D_INNER_ * 4; f += 256) cw_s[f >> 2][f & 3] = conv_w[f];
  if (tid < D_INNER_) cb_s[tid] = conv_b[tid];
  __syncthreads();

  // h tile (67 x 128)
  for (int f = tid; f < 67 * D_MODEL_; f += 256) {
    int r = f >> 7, d = f & 127;
    float acc = ip_b[d];
#pragma unroll
    for (int c = 0; c < C_IN_; ++c) acc += xa[r][c] * ipw_s[d][c];
    h_s[r][d] = acc;
  }
  __syncthreads();

  // xm tile (67 x 256) = h @ W1.T ; main 64 rows as 8x8 micro-tiles, 3 halo rows 1 col/thread
  const int tr = tid >> 5, tc = tid & 31;
  float acc[8][8];
#pragma unroll
  for (int i = 0; i < 8; ++i)
#pragma unroll
    for (int j = 0; j < 8; ++j) acc[i][j] = 0.f;
  float hacc[3] = {0.f, 0.f, 0.f};

  for (int kc = 0; kc < D_MODEL_; kc += 32) {
    {
      const float* wp = in_proj_w + (size_t)tid * D_MODEL_ + kc;  // rows 0..255 = xm half
#pragma unroll
      for (int kk = 0; kk < 32; ++kk) w_s[tid][kk] = wp[kk];
    }
    __syncthreads();
    for (int kk = 0; kk < 32; ++kk) {
      float a[8], bb[8];
#pragma unroll
      for (int i = 0; i < 8; ++i) a[i] = h_s[3 + tr * 8 + i][kc + kk];
#pragma unroll
      for (int j = 0; j < 8; ++j) bb[j] = w_s[tc + 32 * j][kk];
#pragma unroll
      for (int i = 0; i < 8; ++i)
#pragma unroll
        for (int j = 0; j < 8; ++j) acc[i][j] += a[i] * bb[j];
      float bw = w_s[tid][kk];
      hacc[0] += h_s[0][kc + kk] * bw;
      hacc[1] += h_s[1][kc + kk] * bw;
      hacc[2] += h_s[2][kc + kk] * bw;
    }
    __syncthreads();
  }

#pragma unroll
  for (int i = 0; i < 8; ++i)
#pragma unroll
    for (int j = 0; j < 8; ++j) xm_s[3 + tr * 8 + i][tc + 32 * j] = acc[i][j];
#pragma unroll
  for (int hr = 0; hr < 3; ++hr)
    xm_s[hr][tid] = (t0 == 0) ? 0.f : hacc[hr];   // t<0 pad rows are exact zeros
  __syncthreads();

  // conv(4-tap causal) + silu + store u
#pragma unroll
  for (int i = 0; i < 8; ++i) {
    int j = tr * 8 + i;
    int t = t0 + j;
    if (t < T_LEN) {
#pragma unroll
      for (int jj = 0; jj < 8; ++jj) {
        int n = tc + 32 * jj;
        float s = cb_s[n];
#pragma unroll
        for (int k = 0; k < 4; ++k) s += xm_s[j + k][n] * cw_s[n][k];
        u_out[((size_t)b * T_LEN + t) * D_INNER_ + n] = s * sigmoid_f(s);
      }
    }
  }
}

// K3: dbc = u @ x_proj_w[0:24].T ; delta = softplus(dt @ dt_proj_w.T + b) ; emit delta, Bm
__global__ __launch_bounds__(256) void k3_delta(
    const float* __restrict__ u, const float* __restrict__ x_proj_w,
    const float* __restrict__ dt_proj_w, const float* __restrict__ dt_proj_b,
    float* __restrict__ delta_out, float* __restrict__ bm_out)
{
  __shared__ float u_s[64][257];
  __shared__ float xp_s[24][257];
  __shared__ float dbc_s[64][25];
  __shared__ float dtw_s[256][9];
  const int row0 = blockIdx.x * 64;   // 1000 blocks, 64000 rows exactly
  const int tid = threadIdx.x;

  for (int f = tid; f < 64 * 256; f += 256) {
    int r = f >> 8, c = f & 255;
    u_s[r][c] = u[((size_t)row0 + r) * 256 + c];
  }
  for (int f = tid; f < 24 * 256; f += 256) {
    int r = f >> 8, c = f & 255;
    xp_s[r][c] = x_proj_w[f];
  }
  for (int f = tid; f < 256 * 8; f += 256) dtw_s[f >> 3][f & 7] = dt_proj_w[f];
  __syncthreads();

  {
    const int r = tid >> 2, q = tid & 3;    // thread -> row r, cols q+4*jj (jj<6)
    float acc[6] = {0.f, 0.f, 0.f, 0.f, 0.f, 0.f};
    for (int k = 0; k < 256; ++k) {
      float uv = u_s[r][k];
#pragma unroll
      for (int jj = 0; jj < 6; ++jj) acc[jj] += uv * xp_s[q + 4 * jj][k];
    }
#pragma unroll
    for (int jj = 0; jj < 6; ++jj) {
      int col = q + 4 * jj;
      dbc_s[r][col] = acc[jj];
      if (col >= DT_RANK_)
        bm_out[((size_t)row0 + r) * 16 + (col - DT_RANK_)] = acc[jj];
    }
  }
  __syncthreads();

  const int tr = tid >> 5, tc = tid & 31;
#pragma unroll
  for (int i = 0; i < 8; ++i) {
    int r = tr * 8 + i;
    float dtv[8];
#pragma unroll
    for (int j = 0; j < 8; ++j) dtv[j] = dbc_s[r][j];
#pragma unroll
    for (int jj = 0; jj < 8; ++jj) {
      int n = tc + 32 * jj;
      float pre = dt_proj_b[n];
#pragma unroll
      for (int j = 0; j < 8; ++j) pre += dtv[j] * dtw_s[n][j];
      delta_out[((size_t)row0 + r) * 256 + n] = softplus_f(pre);
    }
  }
}

// K4: sequential selective scan; thread = (b,d) channel, 16 states in registers.
__global__ __launch_bounds__(64) void k4_scan(
    const float* __restrict__ delta, const float* __restrict__ u,
    const float* __restrict__ bm, const float* __restrict__ A_log,
    float* __restrict__ state_out)
{
  const int b = blockIdx.x >> 2;
  const int d = ((blockIdx.x & 3) << 6) + threadIdx.x;
  __shared__ float bs[200][16];
  float A[16];
#pragma unroll
  for (int n = 0; n < 16; ++n) A[n] = -expf(A_log[(size_t)d * 16 + n]);
  float s[16];
#pragma unroll
  for (int n = 0; n < 16; ++n) s[n] = 0.f;
  const float* dp = delta + (size_t)b * T_LEN * 256 + d;
  const float* up = u + (size_t)b * T_LEN * 256 + d;
  const float* bp = bm + (size_t)b * T_LEN * 16;
  for (int c0 = 0; c0 < T_LEN; c0 += 200) {
    __syncthreads();
    for (int f = threadIdx.x; f < 200 * 16; f += 64)
      ((float*)bs)[f] = bp[(size_t)c0 * 16 + f];
    __syncthreads();
    for (int tt = 0; tt < 200; ++tt) {
      const size_t off = (size_t)(c0 + tt) * 256;
      float dlt = dp[off];
      float du = dlt * up[off];
#pragma unroll
      for (int n = 0; n < 16; ++n)
        s[n] = expf(dlt * A[n]) * s[n] + du * bs[tt][n];
    }
  }
#pragma unroll
  for (int n = 0; n < 16; ++n)
    state_out[((size_t)b * 256 + d) * 16 + n] = s[n];
}

// K5: per-batch head — z_last, Cm_last, y_last, out_proj, fc1, fc2. One block per b.
__global__ __launch_bounds__(256) void k5_head(
    const float* __restrict__ x, const float* __restrict__ ip_w,
    const float* __restrict__ ip_b, const float* __restrict__ in_proj_w,
    const float* __restrict__ x_proj_w, const float* __restrict__ u,
    const float* __restrict__ state, const float* __restrict__ D_skip,
    const float* __restrict__ out_proj_w, const float* __restrict__ fc1_w,
    const float* __restrict__ fc1_b, const float* __restrict__ fc2_w,
    const float* __restrict__ fc2_b, float* __restrict__ out)
{
  const int b = blockIdx.x, tid = threadIdx.x;
  __shared__ float hl[128], ul[256], zs[256], cm[16], yv[256], ov[128], hid[64];
  if (tid < 128) {
    float acc = ip_b[tid];
    const float* xr = x + ((size_t)b * T_LEN + (T_LEN - 1)) * C_IN_;
#pragma unroll
    for (int c = 0; c < C_IN_; ++c) acc += xr[c] * ip_w[tid * C_IN_ + c];
    hl[tid] = acc;
  }
  ul[tid] = u[((size_t)b * T_LEN + (T_LEN - 1)) * 256 + tid];
  __syncthreads();
  {
    float acc = 0.f;
    const float* w = in_proj_w + (size_t)(256 + tid) * 128;
    for (int k = 0; k < 128; ++k) acc += hl[k] * w[k];
    zs[tid] = acc * sigmoid_f(acc);
  }
  if (tid < 16) {
    float acc = 0.f;
    const float* w = x_proj_w + (size_t)(24 + tid) * 256;
    for (int k = 0; k < 256; ++k) acc += ul[k] * w[k];
    cm[tid] = acc;
  }
  __syncthreads();
  {
    const float* st = state + ((size_t)b * 256 + tid) * 16;
    float acc = 0.f;
#pragma unroll
    for (int n = 0; n < 16; ++n) acc += st[n] * cm[n];
    yv[tid] = (acc + ul[tid] * D_skip[tid]) * zs[tid];
  }
  __syncthreads();
  if (tid < 128) {
    float acc = 0.f;
    const float* w = out_proj_w + (size_t)tid * 256;
    for (int k = 0; k < 256; ++k) acc += yv[k] * w[k];
    ov[tid] = acc;
  }
  __syncthreads();
  if (tid < 64) {
    float acc = fc1_b[tid];
    const float* w = fc1_w + (size_t)tid * 128;
    for (int k = 0; k < 128; ++k) acc += ov[k] * w[k];
    hid[tid] = fmaxf(acc, 0.f);
  }
  __syncthreads();
  if (tid < N_CLS) {
    float acc = fc2_b[tid];
    const float* w = fc2_w + (size_t)tid * 64;
    for (int k = 0; k < 64; ++k) acc += hid[k] * w[k];
    out[b * N_CLS + tid] = acc;
  }
}

extern "C" void kernel_launch(void* const* d_in, const int* in_sizes, int n_in,
                              void* d_out, int out_size, void* d_ws, size_t ws_size,
                              hipStream_t stream) {
  (void)in_sizes; (void)n_in; (void)out_size; (void)ws_size;
  const float* x         = (const float*)d_in[0];
  const float* ip_w      = (const float*)d_in[1];
  const float* ip_b      = (const float*)d_in[2];
  const float* in_proj_w = (const float*)d_in[3];
  const float* conv_w    = (const float*)d_in[4];
  const float* conv_b    = (const float*)d_in[5];
  const float* x_proj_w  = (const float*)d_in[6];
  const float* dt_proj_w = (const float*)d_in[7];
  const float* dt_proj_b = (const float*)d_in[8];
  const float* A_log     = (const float*)d_in[9];
  const float* D_skip    = (const float*)d_in[10];
  const float* out_proj_w= (const float*)d_in[11];
  const float* fc1_w     = (const float*)d_in[12];
  const float* fc1_b     = (const float*)d_in[13];
  const float* fc2_w     = (const float*)d_in[14];
  const float* fc2_b     = (const float*)d_in[15];
  float* out = (float*)d_out;

  float* u     = (float*)d_ws;                       // 64000*256 f32
  float* delta = u + (size_t)64000 * 256;            // 64000*256 f32
  float* bm    = delta + (size_t)64000 * 256;        // 64000*16 f32
  float* state = bm + (size_t)64000 * 16;            // 64*256*16 f32

  k1_u<<<dim3(16, 64), 256, 0, stream>>>(x, ip_w, ip_b, in_proj_w, conv_w, conv_b, u);
  k3_delta<<<1000, 256, 0, stream>>>(u, x_proj_w, dt_proj_w, dt_proj_b, delta, bm);
  k4_scan<<<256, 64, 0, stream>>>(delta, u, bm, A_log, state);
  k5_head<<<64, 256, 0, stream>>>(x, ip_w, ip_b, in_proj_w, x_proj_w, u, state,
                                  D_skip, out_proj_w, fc1_w, fc1_b, fc2_w, fc2_b, out);
}

// Round 2
// 475.883 us; speedup vs baseline: 2.3966x; 2.3966x over previous
//
#include <hip/hip_runtime.h>
#include <cstddef>

#define T_LEN 1000
#define B_SZ 64
#define C_IN_ 12
#define D_MODEL_ 128
#define D_INNER_ 256
#define D_STATE_ 16
#define DT_RANK_ 8
#define N_CLS 5
#define TC_ 200   // scan time-chunk staged in LDS

__device__ __forceinline__ float sigmoid_f(float x) {
  if (x >= 0.f) return 1.f / (1.f + expf(-x));
  float e = expf(x);
  return e / (1.f + e);
}
__device__ __forceinline__ float softplus_f(float x) {
  return (x > 0.f) ? (x + log1pf(expf(-x))) : log1pf(expf(x));
}

// K1: fused  h = x@ip_w.T + ip_b  ->  xm = h@W1.T  -> causal depthwise conv -> silu -> u
// Tile: 64 output t-rows per block, 3-row halo recomputed (xm rows t0-3..t0+63).
__global__ __launch_bounds__(256) void k1_u(
    const float* __restrict__ x, const float* __restrict__ ip_w,
    const float* __restrict__ ip_b, const float* __restrict__ in_proj_w,
    const float* __restrict__ conv_w, const float* __restrict__ conv_b,
    float* __restrict__ u_out)
{
  __shared__ float h_s[67][129];    // pad 129: 8-row stride -> 2-way bank alias (free)
  __shared__ float xm_s[67][257];
  __shared__ float w_s[256][33];    // W1 chunk, n-major, pad 33 (coprime with 32)
  __shared__ float xa[67][C_IN_];
  __shared__ float ipw_s[D_MODEL_][C_IN_];
  __shared__ float cw_s[D_INNER_][4];
  __shared__ float cb_s[D_INNER_];

  const int tile = blockIdx.x;   // 0..15
  const int b    = blockIdx.y;   // 0..63
  const int t0   = tile * 64;
  const int tid  = threadIdx.x;

  // stage x rows (with halo, zero-padded), ip_w, conv params
  for (int f = tid; f < 67 * C_IN_; f += 256) {
    int r = f / C_IN_, c = f - r * C_IN_;
    int t = t0 - 3 + r;
    xa[r][c] = (t >= 0 && t < T_LEN) ? x[((size_t)b * T_LEN + t) * C_IN_ + c] : 0.f;
  }
  for (int f = tid; f < D_MODEL_ * C_IN_; f += 256) ipw_s[f / C_IN_][f % C_IN_] = ip_w[f];
  for (int f = tid; f < D_INNER_ * 4; f += 256) cw_s[f >> 2][f & 3] = conv_w[f];
  if (tid < D_INNER_) cb_s[tid] = conv_b[tid];
  __syncthreads();

  // h tile (67 x 128)
  for (int f = tid; f < 67 * D_MODEL_; f += 256) {
    int r = f >> 7, d = f & 127;
    float acc = ip_b[d];
#pragma unroll
    for (int c = 0; c < C_IN_; ++c) acc += xa[r][c] * ipw_s[d][c];
    h_s[r][d] = acc;
  }
  __syncthreads();

  // xm tile (67 x 256) = h @ W1.T ; main 64 rows as 8x8 micro-tiles, 3 halo rows 1 col/thread
  const int tr = tid >> 5, tc = tid & 31;
  float acc[8][8];
#pragma unroll
  for (int i = 0; i < 8; ++i)
#pragma unroll
    for (int j = 0; j < 8; ++j) acc[i][j] = 0.f;
  float hacc[3] = {0.f, 0.f, 0.f};

  for (int kc = 0; kc < D_MODEL_; kc += 32) {
    {
      const float* wp = in_proj_w + (size_t)tid * D_MODEL_ + kc;  // rows 0..255 = xm half
#pragma unroll
      for (int kk = 0; kk < 32; ++kk) w_s[tid][kk] = wp[kk];
    }
    __syncthreads();
    for (int kk = 0; kk < 32; ++kk) {
      float a[8], bb[8];
#pragma unroll
      for (int i = 0; i < 8; ++i) a[i] = h_s[3 + tr * 8 + i][kc + kk];
#pragma unroll
      for (int j = 0; j < 8; ++j) bb[j] = w_s[tc + 32 * j][kk];
#pragma unroll
      for (int i = 0; i < 8; ++i)
#pragma unroll
        for (int j = 0; j < 8; ++j) acc[i][j] += a[i] * bb[j];
      float bw = w_s[tid][kk];
      hacc[0] += h_s[0][kc + kk] * bw;
      hacc[1] += h_s[1][kc + kk] * bw;
      hacc[2] += h_s[2][kc + kk] * bw;
    }
    __syncthreads();
  }

#pragma unroll
  for (int i = 0; i < 8; ++i)
#pragma unroll
    for (int j = 0; j < 8; ++j) xm_s[3 + tr * 8 + i][tc + 32 * j] = acc[i][j];
#pragma unroll
  for (int hr = 0; hr < 3; ++hr)
    xm_s[hr][tid] = (t0 == 0) ? 0.f : hacc[hr];   // t<0 pad rows are exact zeros
  __syncthreads();

  // conv(4-tap causal) + silu + store u
#pragma unroll
  for (int i = 0; i < 8; ++i) {
    int j = tr * 8 + i;
    int t = t0 + j;
    if (t < T_LEN) {
#pragma unroll
      for (int jj = 0; jj < 8; ++jj) {
        int n = tc + 32 * jj;
        float s = cb_s[n];
#pragma unroll
        for (int k = 0; k < 4; ++k) s += xm_s[j + k][n] * cw_s[n][k];
        u_out[((size_t)b * T_LEN + t) * D_INNER_ + n] = s * sigmoid_f(s);
      }
    }
  }
}

// K3: dbc = u @ x_proj_w[0:24].T ; delta = softplus(dt @ dt_proj_w.T + b) ; emit delta, Bm
__global__ __launch_bounds__(256) void k3_delta(
    const float* __restrict__ u, const float* __restrict__ x_proj_w,
    const float* __restrict__ dt_proj_w, const float* __restrict__ dt_proj_b,
    float* __restrict__ delta_out, float* __restrict__ bm_out)
{
  __shared__ float u_s[64][257];
  __shared__ float xp_s[24][257];
  __shared__ float dbc_s[64][25];
  __shared__ float dtw_s[256][9];
  const int row0 = blockIdx.x * 64;   // 1000 blocks, 64000 rows exactly
  const int tid = threadIdx.x;

  for (int f = tid; f < 64 * 256; f += 256) {
    int r = f >> 8, c = f & 255;
    u_s[r][c] = u[((size_t)row0 + r) * 256 + c];
  }
  for (int f = tid; f < 24 * 256; f += 256) {
    int r = f >> 8, c = f & 255;
    xp_s[r][c] = x_proj_w[f];
  }
  for (int f = tid; f < 256 * 8; f += 256) dtw_s[f >> 3][f & 7] = dt_proj_w[f];
  __syncthreads();

  {
    const int r = tid >> 2, q = tid & 3;    // thread -> row r, cols q+4*jj (jj<6)
    float acc[6] = {0.f, 0.f, 0.f, 0.f, 0.f, 0.f};
    for (int k = 0; k < 256; ++k) {
      float uv = u_s[r][k];
#pragma unroll
      for (int jj = 0; jj < 6; ++jj) acc[jj] += uv * xp_s[q + 4 * jj][k];
    }
#pragma unroll
    for (int jj = 0; jj < 6; ++jj) {
      int col = q + 4 * jj;
      dbc_s[r][col] = acc[jj];
      if (col >= DT_RANK_)
        bm_out[((size_t)row0 + r) * 16 + (col - DT_RANK_)] = acc[jj];
    }
  }
  __syncthreads();

  const int tr = tid >> 5, tc = tid & 31;
#pragma unroll
  for (int i = 0; i < 8; ++i) {
    int r = tr * 8 + i;
    float dtv[8];
#pragma unroll
    for (int j = 0; j < 8; ++j) dtv[j] = dbc_s[r][j];
#pragma unroll
    for (int jj = 0; jj < 8; ++jj) {
      int n = tc + 32 * jj;
      float pre = dt_proj_b[n];
#pragma unroll
      for (int j = 0; j < 8; ++j) pre += dtv[j] * dtw_s[n][j];
      delta_out[((size_t)row0 + r) * 256 + n] = softplus_f(pre);
    }
  }
}

// K4: selective scan, thread = (b, d, n). 16x more waves than R0 (16 waves/CU).
// LDS time-packed [t/4][ch][4] so inner loop is 3x ds_read_b128 per 4 steps.
__global__ __launch_bounds__(256) void k4_scan(
    const float* __restrict__ delta, const float* __restrict__ u,
    const float* __restrict__ bm, const float* __restrict__ A_log,
    float* __restrict__ state_out)
{
  __shared__ float da[TC_ / 4][16][4];   // delta,  indexed [t4][d_local][t&3]
  __shared__ float ua[TC_ / 4][16][4];   // delta*u
  __shared__ float ba[TC_ / 4][16][4];   // Bm,     indexed [t4][n][t&3]

  const int d0 = blockIdx.x * 16;        // 16 d-channels per block
  const int b  = blockIdx.y;
  const int tid = threadIdx.x;
  const int dl = tid >> 4;               // 0..15 local d
  const int n  = tid & 15;               // 0..15 state index

  // fold log2(e) into A so the step uses v_exp (2^x) directly
  const float A2 = -expf(A_log[(size_t)(d0 + dl) * 16 + n]) * 1.4426950408889634f;
  float s = 0.f;

  const float* dbase = delta + (size_t)b * T_LEN * 256 + d0;
  const float* ubase = u     + (size_t)b * T_LEN * 256 + d0;
  const float* bbase = bm    + (size_t)b * T_LEN * 16;

  for (int t0 = 0; t0 < T_LEN; t0 += TC_) {
    __syncthreads();
    for (int f = tid; f < TC_ * 16; f += 256) {
      int t = f >> 4, dj = f & 15;
      float dv = dbase[(size_t)(t0 + t) * 256 + dj];
      float uv = ubase[(size_t)(t0 + t) * 256 + dj];
      float bv = bbase[(size_t)(t0 + t) * 16 + dj];
      da[t >> 2][dj][t & 3] = dv;
      ua[t >> 2][dj][t & 3] = dv * uv;
      ba[t >> 2][dj][t & 3] = bv;
    }
    __syncthreads();
#pragma unroll 2
    for (int t4 = 0; t4 < TC_ / 4; ++t4) {
      float4 dv = *(const float4*)&da[t4][dl][0];
      float4 uv = *(const float4*)&ua[t4][dl][0];
      float4 bv = *(const float4*)&ba[t4][n][0];
      s = exp2f(dv.x * A2) * s + uv.x * bv.x;
      s = exp2f(dv.y * A2) * s + uv.y * bv.y;
      s = exp2f(dv.z * A2) * s + uv.z * bv.z;
      s = exp2f(dv.w * A2) * s + uv.w * bv.w;
    }
  }
  state_out[((size_t)b * 256 + d0 + dl) * 16 + n] = s;
}

// K5: per-batch head — z_last, Cm_last, y_last, out_proj, fc1, fc2. One block per b.
__global__ __launch_bounds__(256) void k5_head(
    const float* __restrict__ x, const float* __restrict__ ip_w,
    const float* __restrict__ ip_b, const float* __restrict__ in_proj_w,
    const float* __restrict__ x_proj_w, const float* __restrict__ u,
    const float* __restrict__ state, const float* __restrict__ D_skip,
    const float* __restrict__ out_proj_w, const float* __restrict__ fc1_w,
    const float* __restrict__ fc1_b, const float* __restrict__ fc2_w,
    const float* __restrict__ fc2_b, float* __restrict__ out)
{
  const int b = blockIdx.x, tid = threadIdx.x;
  __shared__ float hl[128], ul[256], zs[256], cm[16], yv[256], ov[128], hid[64];
  if (tid < 128) {
    float acc = ip_b[tid];
    const float* xr = x + ((size_t)b * T_LEN + (T_LEN - 1)) * C_IN_;
#pragma unroll
    for (int c = 0; c < C_IN_; ++c) acc += xr[c] * ip_w[tid * C_IN_ + c];
    hl[tid] = acc;
  }
  ul[tid] = u[((size_t)b * T_LEN + (T_LEN - 1)) * 256 + tid];
  __syncthreads();
  {
    float acc = 0.f;
    const float* w = in_proj_w + (size_t)(256 + tid) * 128;
    for (int k = 0; k < 128; ++k) acc += hl[k] * w[k];
    zs[tid] = acc * sigmoid_f(acc);
  }
  if (tid < 16) {
    float acc = 0.f;
    const float* w = x_proj_w + (size_t)(24 + tid) * 256;
    for (int k = 0; k < 256; ++k) acc += ul[k] * w[k];
    cm[tid] = acc;
  }
  __syncthreads();
  {
    const float* st = state + ((size_t)b * 256 + tid) * 16;
    float acc = 0.f;
#pragma unroll
    for (int n = 0; n < 16; ++n) acc += st[n] * cm[n];
    yv[tid] = (acc + ul[tid] * D_skip[tid]) * zs[tid];
  }
  __syncthreads();
  if (tid < 128) {
    float acc = 0.f;
    const float* w = out_proj_w + (size_t)tid * 256;
    for (int k = 0; k < 256; ++k) acc += yv[k] * w[k];
    ov[tid] = acc;
  }
  __syncthreads();
  if (tid < 64) {
    float acc = fc1_b[tid];
    const float* w = fc1_w + (size_t)tid * 128;
    for (int k = 0; k < 128; ++k) acc += ov[k] * w[k];
    hid[tid] = fmaxf(acc, 0.f);
  }
  __syncthreads();
  if (tid < N_CLS) {
    float acc = fc2_b[tid];
    const float* w = fc2_w + (size_t)tid * 64;
    for (int k = 0; k < 64; ++k) acc += hid[k] * w[k];
    out[b * N_CLS + tid] = acc;
  }
}

extern "C" void kernel_launch(void* const* d_in, const int* in_sizes, int n_in,
                              void* d_out, int out_size, void* d_ws, size_t ws_size,
                              hipStream_t stream) {
  (void)in_sizes; (void)n_in; (void)out_size; (void)ws_size;
  const float* x         = (const float*)d_in[0];
  const float* ip_w      = (const float*)d_in[1];
  const float* ip_b      = (const float*)d_in[2];
  const float* in_proj_w = (const float*)d_in[3];
  const float* conv_w    = (const float*)d_in[4];
  const float* conv_b    = (const float*)d_in[5];
  const float* x_proj_w  = (const float*)d_in[6];
  const float* dt_proj_w = (const float*)d_in[7];
  const float* dt_proj_b = (const float*)d_in[8];
  const float* A_log     = (const float*)d_in[9];
  const float* D_skip    = (const float*)d_in[10];
  const float* out_proj_w= (const float*)d_in[11];
  const float* fc1_w     = (const float*)d_in[12];
  const float* fc1_b     = (const float*)d_in[13];
  const float* fc2_w     = (const float*)d_in[14];
  const float* fc2_b     = (const float*)d_in[15];
  float* out = (float*)d_out;

  float* u     = (float*)d_ws;                       // 64000*256 f32
  float* delta = u + (size_t)64000 * 256;            // 64000*256 f32
  float* bm    = delta + (size_t)64000 * 256;        // 64000*16 f32
  float* state = bm + (size_t)64000 * 16;            // 64*256*16 f32

  k1_u<<<dim3(16, 64), 256, 0, stream>>>(x, ip_w, ip_b, in_proj_w, conv_w, conv_b, u);
  k3_delta<<<1000, 256, 0, stream>>>(u, x_proj_w, dt_proj_w, dt_proj_b, delta, bm);
  k4_scan<<<dim3(16, 64), 256, 0, stream>>>(delta, u, bm, A_log, state);
  k5_head<<<64, 256, 0, stream>>>(x, ip_w, ip_b, in_proj_w, x_proj_w, u, state,
                                  D_skip, out_proj_w, fc1_w, fc1_b, fc2_w, fc2_b, out);
}

// Round 3
// 363.370 us; speedup vs baseline: 3.1387x; 1.3096x over previous
//
#include <hip/hip_runtime.h>
#include <cstddef>

#define T_LEN 1000
#define B_SZ 64
#define C_IN_ 12
#define D_MODEL_ 128
#define D_INNER_ 256
#define D_STATE_ 16
#define DT_RANK_ 8
#define N_CLS 5
#define TC_ 200   // scan time-chunk staged in LDS

__device__ __forceinline__ float sigmoid_f(float x) {
  if (x >= 0.f) return 1.f / (1.f + expf(-x));
  float e = expf(x);
  return e / (1.f + e);
}
__device__ __forceinline__ float softplus_f(float x) {
  return (x > 0.f) ? (x + log1pf(expf(-x))) : log1pf(expf(x));
}

// K1: fused  h = x@ip_w.T + ip_b  ->  xm = h@W1.T  -> causal depthwise conv -> silu -> u
__global__ __launch_bounds__(256) void k1_u(
    const float* __restrict__ x, const float* __restrict__ ip_w,
    const float* __restrict__ ip_b, const float* __restrict__ in_proj_w,
    const float* __restrict__ conv_w, const float* __restrict__ conv_b,
    float* __restrict__ u_out)
{
  __shared__ float h_s[67][129];
  __shared__ float xm_s[67][257];
  __shared__ float w_s[256][33];
  __shared__ float xa[67][C_IN_];
  __shared__ float ipw_s[D_MODEL_][C_IN_];
  __shared__ float cw_s[D_INNER_][4];
  __shared__ float cb_s[D_INNER_];

  const int tile = blockIdx.x;   // 0..15
  const int b    = blockIdx.y;   // 0..63
  const int t0   = tile * 64;
  const int tid  = threadIdx.x;

  for (int f = tid; f < 67 * C_IN_; f += 256) {
    int r = f / C_IN_, c = f - r * C_IN_;
    int t = t0 - 3 + r;
    xa[r][c] = (t >= 0 && t < T_LEN) ? x[((size_t)b * T_LEN + t) * C_IN_ + c] : 0.f;
  }
  for (int f = tid; f < D_MODEL_ * C_IN_; f += 256) ipw_s[f / C_IN_][f % C_IN_] = ip_w[f];
  for (int f = tid; f < D_INNER_ * 4; f += 256) cw_s[f >> 2][f & 3] = conv_w[f];
  if (tid < D_INNER_) cb_s[tid] = conv_b[tid];
  __syncthreads();

  for (int f = tid; f < 67 * D_MODEL_; f += 256) {
    int r = f >> 7, d = f & 127;
    float acc = ip_b[d];
#pragma unroll
    for (int c = 0; c < C_IN_; ++c) acc += xa[r][c] * ipw_s[d][c];
    h_s[r][d] = acc;
  }
  __syncthreads();

  const int tr = tid >> 5, tc = tid & 31;
  float acc[8][8];
#pragma unroll
  for (int i = 0; i < 8; ++i)
#pragma unroll
    for (int j = 0; j < 8; ++j) acc[i][j] = 0.f;
  float hacc[3] = {0.f, 0.f, 0.f};

  for (int kc = 0; kc < D_MODEL_; kc += 32) {
    {
      const float* wp = in_proj_w + (size_t)tid * D_MODEL_ + kc;
#pragma unroll
      for (int kk = 0; kk < 32; ++kk) w_s[tid][kk] = wp[kk];
    }
    __syncthreads();
    for (int kk = 0; kk < 32; ++kk) {
      float a[8], bb[8];
#pragma unroll
      for (int i = 0; i < 8; ++i) a[i] = h_s[3 + tr * 8 + i][kc + kk];
#pragma unroll
      for (int j = 0; j < 8; ++j) bb[j] = w_s[tc + 32 * j][kk];
#pragma unroll
      for (int i = 0; i < 8; ++i)
#pragma unroll
        for (int j = 0; j < 8; ++j) acc[i][j] += a[i] * bb[j];
      float bw = w_s[tid][kk];
      hacc[0] += h_s[0][kc + kk] * bw;
      hacc[1] += h_s[1][kc + kk] * bw;
      hacc[2] += h_s[2][kc + kk] * bw;
    }
    __syncthreads();
  }

#pragma unroll
  for (int i = 0; i < 8; ++i)
#pragma unroll
    for (int j = 0; j < 8; ++j) xm_s[3 + tr * 8 + i][tc + 32 * j] = acc[i][j];
#pragma unroll
  for (int hr = 0; hr < 3; ++hr)
    xm_s[hr][tid] = (t0 == 0) ? 0.f : hacc[hr];
  __syncthreads();

#pragma unroll
  for (int i = 0; i < 8; ++i) {
    int j = tr * 8 + i;
    int t = t0 + j;
    if (t < T_LEN) {
#pragma unroll
      for (int jj = 0; jj < 8; ++jj) {
        int n = tc + 32 * jj;
        float s = cb_s[n];
#pragma unroll
        for (int k = 0; k < 4; ++k) s += xm_s[j + k][n] * cw_s[n][k];
        u_out[((size_t)b * T_LEN + t) * D_INNER_ + n] = s * sigmoid_f(s);
      }
    }
  }
}

// K3 v2: lean LDS (~36KB -> 4 blocks/CU). Phase 1: dbc = u @ xp[0:24].T with u
// read straight from global (float4, 8-lane broadcast), 2 rows x 3 cols per
// thread in registers. Phase 2: delta = softplus(dt @ dtw.T + b).
__global__ __launch_bounds__(256) void k3_delta(
    const float* __restrict__ u, const float* __restrict__ x_proj_w,
    const float* __restrict__ dt_proj_w, const float* __restrict__ dt_proj_b,
    float* __restrict__ delta_out, float* __restrict__ bm_out)
{
  __shared__ float4 xp4[24][65];    // pad 65: 3-apart rows land on distinct bank quads
  __shared__ float4 dtw4[256][2];
  __shared__ float dt_s[64][9];
  __shared__ float dtb_s[256];

  const int row0 = blockIdx.x * 64;   // 1000 blocks
  const int tid = threadIdx.x;

  for (int f = tid; f < 24 * 64; f += 256) {
    int c = f >> 6, k4 = f & 63;
    xp4[c][k4] = *(const float4*)&x_proj_w[(size_t)c * 256 + k4 * 4];
  }
  for (int f = tid; f < 512; f += 256) {
    int n = f >> 1, hh = f & 1;
    dtw4[n][hh] = *(const float4*)&dt_proj_w[(size_t)n * 8 + hh * 4];
  }
  dtb_s[tid] = dt_proj_b[tid];
  __syncthreads();

  // phase 1
  {
    const int r2 = tid >> 3, cg = tid & 7;   // rows 2r2,2r2+1 ; cols 3cg..3cg+2
    const int ra = 2 * r2;
    const float4* ua4 = (const float4*)(u + (size_t)(row0 + ra) * 256);
    const float4* ub4 = (const float4*)(u + (size_t)(row0 + ra + 1) * 256);
    float a0 = 0.f, a1 = 0.f, a2 = 0.f, b0 = 0.f, b1 = 0.f, b2 = 0.f;
    for (int k4 = 0; k4 < 64; ++k4) {
      float4 a = ua4[k4], b = ub4[k4];
      float4 w0 = xp4[cg * 3 + 0][k4];
      float4 w1 = xp4[cg * 3 + 1][k4];
      float4 w2 = xp4[cg * 3 + 2][k4];
      a0 += a.x * w0.x + a.y * w0.y + a.z * w0.z + a.w * w0.w;
      a1 += a.x * w1.x + a.y * w1.y + a.z * w1.z + a.w * w1.w;
      a2 += a.x * w2.x + a.y * w2.y + a.z * w2.z + a.w * w2.w;
      b0 += b.x * w0.x + b.y * w0.y + b.z * w0.z + b.w * w0.w;
      b1 += b.x * w1.x + b.y * w1.y + b.z * w1.z + b.w * w1.w;
      b2 += b.x * w2.x + b.y * w2.y + b.z * w2.z + b.w * w2.w;
    }
    float va[2][3] = {{a0, a1, a2}, {b0, b1, b2}};
#pragma unroll
    for (int rr = 0; rr < 2; ++rr)
#pragma unroll
      for (int c = 0; c < 3; ++c) {
        int col = cg * 3 + c;
        int row = ra + rr;
        if (col < 8) dt_s[row][col] = va[rr][c];
        else bm_out[((size_t)(row0 + row)) * 16 + (col - 8)] = va[rr][c];
      }
  }
  __syncthreads();

  // phase 2
  {
    const int r = tid >> 2, q = tid & 3;
    float dtv[8];
#pragma unroll
    for (int j = 0; j < 8; ++j) dtv[j] = dt_s[r][j];
    float* drow = delta_out + (size_t)(row0 + r) * 256;
    for (int cc = 0; cc < 64; ++cc) {
      int n = 4 * cc + q;
      float4 w0 = dtw4[n][0], w1 = dtw4[n][1];
      float pre = dtb_s[n]
        + dtv[0] * w0.x + dtv[1] * w0.y + dtv[2] * w0.z + dtv[3] * w0.w
        + dtv[4] * w1.x + dtv[5] * w1.y + dtv[6] * w1.z + dtv[7] * w1.w;
      drow[n] = softplus_f(pre);
    }
  }
}

// K4: selective scan, thread = (b, d, n); float4 global staging.
__global__ __launch_bounds__(256) void k4_scan(
    const float* __restrict__ delta, const float* __restrict__ u,
    const float* __restrict__ bm, const float* __restrict__ A_log,
    float* __restrict__ state_out)
{
  __shared__ float da[TC_ / 4][16][4];
  __shared__ float ua[TC_ / 4][16][4];
  __shared__ float ba[TC_ / 4][16][4];

  const int d0 = blockIdx.x * 16;
  const int b  = blockIdx.y;
  const int tid = threadIdx.x;
  const int dl = tid >> 4;
  const int n  = tid & 15;

  const float A2 = -expf(A_log[(size_t)(d0 + dl) * 16 + n]) * 1.4426950408889634f;
  float s = 0.f;

  const float* dbase = delta + (size_t)b * T_LEN * 256 + d0;
  const float* ubase = u     + (size_t)b * T_LEN * 256 + d0;
  const float* bbase = bm    + (size_t)b * T_LEN * 16;

  for (int t0 = 0; t0 < T_LEN; t0 += TC_) {
    __syncthreads();
    for (int f = tid; f < TC_ * 4; f += 256) {
      int t = f >> 2, g = f & 3;
      float4 dv = *(const float4*)&dbase[(size_t)(t0 + t) * 256 + g * 4];
      float4 uv = *(const float4*)&ubase[(size_t)(t0 + t) * 256 + g * 4];
      float4 bv = *(const float4*)&bbase[(size_t)(t0 + t) * 16 + g * 4];
      int t4 = t >> 2, t3 = t & 3, d4 = g * 4;
      da[t4][d4 + 0][t3] = dv.x; da[t4][d4 + 1][t3] = dv.y;
      da[t4][d4 + 2][t3] = dv.z; da[t4][d4 + 3][t3] = dv.w;
      ua[t4][d4 + 0][t3] = dv.x * uv.x; ua[t4][d4 + 1][t3] = dv.y * uv.y;
      ua[t4][d4 + 2][t3] = dv.z * uv.z; ua[t4][d4 + 3][t3] = dv.w * uv.w;
      ba[t4][d4 + 0][t3] = bv.x; ba[t4][d4 + 1][t3] = bv.y;
      ba[t4][d4 + 2][t3] = bv.z; ba[t4][d4 + 3][t3] = bv.w;
    }
    __syncthreads();
#pragma unroll 2
    for (int t4 = 0; t4 < TC_ / 4; ++t4) {
      float4 dv = *(const float4*)&da[t4][dl][0];
      float4 uv = *(const float4*)&ua[t4][dl][0];
      float4 bv = *(const float4*)&ba[t4][n][0];
      s = exp2f(dv.x * A2) * s + uv.x * bv.x;
      s = exp2f(dv.y * A2) * s + uv.y * bv.y;
      s = exp2f(dv.z * A2) * s + uv.z * bv.z;
      s = exp2f(dv.w * A2) * s + uv.w * bv.w;
    }
  }
  state_out[((size_t)b * 256 + d0 + dl) * 16 + n] = s;
}

// K5: per-batch head.
__global__ __launch_bounds__(256) void k5_head(
    const float* __restrict__ x, const float* __restrict__ ip_w,
    const float* __restrict__ ip_b, const float* __restrict__ in_proj_w,
    const float* __restrict__ x_proj_w, const float* __restrict__ u,
    const float* __restrict__ state, const float* __restrict__ D_skip,
    const float* __restrict__ out_proj_w, const float* __restrict__ fc1_w,
    const float* __restrict__ fc1_b, const float* __restrict__ fc2_w,
    const float* __restrict__ fc2_b, float* __restrict__ out)
{
  const int b = blockIdx.x, tid = threadIdx.x;
  __shared__ float hl[128], ul[256], zs[256], cm[16], yv[256], ov[128], hid[64];
  if (tid < 128) {
    float acc = ip_b[tid];
    const float* xr = x + ((size_t)b * T_LEN + (T_LEN - 1)) * C_IN_;
#pragma unroll
    for (int c = 0; c < C_IN_; ++c) acc += xr[c] * ip_w[tid * C_IN_ + c];
    hl[tid] = acc;
  }
  ul[tid] = u[((size_t)b * T_LEN + (T_LEN - 1)) * 256 + tid];
  __syncthreads();
  {
    float acc = 0.f;
    const float* w = in_proj_w + (size_t)(256 + tid) * 128;
    for (int k = 0; k < 128; ++k) acc += hl[k] * w[k];
    zs[tid] = acc * sigmoid_f(acc);
  }
  if (tid < 16) {
    float acc = 0.f;
    const float* w = x_proj_w + (size_t)(24 + tid) * 256;
    for (int k = 0; k < 256; ++k) acc += ul[k] * w[k];
    cm[tid] = acc;
  }
  __syncthreads();
  {
    const float* st = state + ((size_t)b * 256 + tid) * 16;
    float acc = 0.f;
#pragma unroll
    for (int n = 0; n < 16; ++n) acc += st[n] * cm[n];
    yv[tid] = (acc + ul[tid] * D_skip[tid]) * zs[tid];
  }
  __syncthreads();
  if (tid < 128) {
    float acc = 0.f;
    const float* w = out_proj_w + (size_t)tid * 256;
    for (int k = 0; k < 256; ++k) acc += yv[k] * w[k];
    ov[tid] = acc;
  }
  __syncthreads();
  if (tid < 64) {
    float acc = fc1_b[tid];
    const float* w = fc1_w + (size_t)tid * 128;
    for (int k = 0; k < 128; ++k) acc += ov[k] * w[k];
    hid[tid] = fmaxf(acc, 0.f);
  }
  __syncthreads();
  if (tid < N_CLS) {
    float acc = fc2_b[tid];
    const float* w = fc2_w + (size_t)tid * 64;
    for (int k = 0; k < 64; ++k) acc += hid[k] * w[k];
    out[b * N_CLS + tid] = acc;
  }
}

extern "C" void kernel_launch(void* const* d_in, const int* in_sizes, int n_in,
                              void* d_out, int out_size, void* d_ws, size_t ws_size,
                              hipStream_t stream) {
  (void)in_sizes; (void)n_in; (void)out_size; (void)ws_size;
  const float* x         = (const float*)d_in[0];
  const float* ip_w      = (const float*)d_in[1];
  const float* ip_b      = (const float*)d_in[2];
  const float* in_proj_w = (const float*)d_in[3];
  const float* conv_w    = (const float*)d_in[4];
  const float* conv_b    = (const float*)d_in[5];
  const float* x_proj_w  = (const float*)d_in[6];
  const float* dt_proj_w = (const float*)d_in[7];
  const float* dt_proj_b = (const float*)d_in[8];
  const float* A_log     = (const float*)d_in[9];
  const float* D_skip    = (const float*)d_in[10];
  const float* out_proj_w= (const float*)d_in[11];
  const float* fc1_w     = (const float*)d_in[12];
  const float* fc1_b     = (const float*)d_in[13];
  const float* fc2_w     = (const float*)d_in[14];
  const float* fc2_b     = (const float*)d_in[15];
  float* out = (float*)d_out;

  float* u     = (float*)d_ws;
  float* delta = u + (size_t)64000 * 256;
  float* bm    = delta + (size_t)64000 * 256;
  float* state = bm + (size_t)64000 * 16;

  k1_u<<<dim3(16, 64), 256, 0, stream>>>(x, ip_w, ip_b, in_proj_w, conv_w, conv_b, u);
  k3_delta<<<1000, 256, 0, stream>>>(u, x_proj_w, dt_proj_w, dt_proj_b, delta, bm);
  k4_scan<<<dim3(16, 64), 256, 0, stream>>>(delta, u, bm, A_log, state);
  k5_head<<<64, 256, 0, stream>>>(x, ip_w, ip_b, in_proj_w, x_proj_w, u, state,
                                  D_skip, out_proj_w, fc1_w, fc1_b, fc2_w, fc2_b, out);
}